// Round 7
// baseline (10231.850 us; speedup 1.0000x reference)
//
#include <hip/hip_runtime.h>
#include <math.h>

#define BDIM 1024
#define DDIM 512
#define VDIM 128
#define TDIM 201
#define FD   2048            // 4*D
#define LN_EPS 1e-5f
#define LOSCALE 4096.0f
#define INV_LOSCALE (1.0f/4096.0f)

// ws layout in floats
#define OFF_CTX 524288       // B*D    context (constant)            [read-only in loop]
#define OFF_E   1048576      // V*FD   E = embed@W_ih^T + b_ih+b_hh  [read-only in loop]
#define OFF_CP  1310720      // B*V    ctx @ proj^T                  [read-only in loop]
#define OFF_PART 1441792     // 1024*8 u64 partial argmax            [L3-coherent]
#define OFF_ABL 1572864      // 2 MB: A halves, LOCAL copies (plain store / sc0 read)
#define OFF_ABR 2097152      // 2 MB: A halves, L3 copies (sc0sc1 both sides)
#define OFF_BHI 4194304      // B hi frags                           [read-only in loop]
#define OFF_BLO 4751360      // B lo frags                           [read-only in loop]
// A half-buffer layout (per group g, half h in {0,1}):
//   byte base = (g*64 + h*32)*1024 ; hi 16 KB then lo 16 KB
//   within: ((mt*8 + ktl)*64 + lane)*16 + elem*2   (kt = h*8 + ktl)

typedef _Float16 v8hf __attribute__((ext_vector_type(8)));
typedef float    v4f  __attribute__((ext_vector_type(4)));
typedef unsigned long long u64;

#define AGENT __HIP_MEMORY_SCOPE_AGENT
#define RLX   __ATOMIC_RELAXED

// 32 group barriers (128 B apart) + rendezvous counter + placement map.
// Reset by k_init (stream-ordered before k_loop) -> replay-safe.
__device__ unsigned int g_bar[32 * 32];
__device__ unsigned int g_cnt;
__device__ int g_xcd[256];

// L3-coherent helpers (sc0 sc1: bypass L1+L2, coherent point = L3). No cache
// fences anywhere -> read-only L2 sets (B, E, CP, ctx) stay warm all steps.
__device__ __forceinline__ u64 ld8_l3(const void* p) {
    u64 r;
    asm volatile("global_load_dwordx2 %0, %1, off sc0 sc1" : "=v"(r) : "v"(p) : "memory");
    asm volatile("s_waitcnt vmcnt(0)" ::: "memory");
    __builtin_amdgcn_sched_barrier(0);
    return r;
}
__device__ __forceinline__ void st8_l3(void* p, u64 v) {
    asm volatile("global_store_dwordx2 %0, %1, off sc0 sc1" :: "v"(p), "v"(v) : "memory");
}
__device__ __forceinline__ void st16_l3(void* p, v4f v) {
    asm volatile("global_store_dwordx4 %0, %1, off sc0 sc1" :: "v"(p), "v"(v) : "memory");
}
// Streaming 4B store: no L2 allocate -> no fill-fetch, no writeback, no
// B-eviction. Used ONLY for `out` (host-visible after kernel end).
__device__ __forceinline__ void st4_stream(float* p, float v) {
    asm volatile("global_store_dword %0, %1, off sc0 sc1" :: "v"(p), "v"(v) : "memory");
}

// Group barrier (8 blocks, possibly spanning 2 XCDs). The explicit vmcnt
// drain covers inline-asm stores; atomics are agent-scope (L3). Bounded
// spin: logic bugs fail fast (wrong results), never a harness hang.
__device__ __forceinline__ void group_barrier(unsigned int* bar, unsigned int target)
{
    asm volatile("s_waitcnt vmcnt(0)" ::: "memory");
    __syncthreads();
    if (threadIdx.x == 0) {
        __hip_atomic_fetch_add(bar, 1u, RLX, AGENT);
        unsigned int spins = 0;
        while (__hip_atomic_load(bar, RLX, AGENT) < target) {
            __builtin_amdgcn_s_sleep(1);
            if (++spins > (1u << 20)) break;
        }
    }
    __syncthreads();
    asm volatile("" ::: "memory");
    __builtin_amdgcn_sched_barrier(0);
}

// B fragment layout (16x16x32 f16 MFMA), fragment-major over full K:
//   lane l holds W[n=nt*16+(l&15)][k=kt*32+(l>>4)*8+j]
__device__ __forceinline__ void split_write(float x, _Float16* hiArr, _Float16* loArr,
                                            int row, int k)
{
    _Float16 hi = (_Float16)x;
    _Float16 lo = (_Float16)((x - (float)hi) * LOSCALE);
    int lane = (row & 15) | (((k >> 3) & 3) << 4);
    size_t idx = ((size_t)((row >> 4) * 16 + (k >> 5)) * 64 + lane) * 8 + (k & 7);
    hiArr[idx] = hi;
    loArr[idx] = lo;
}

// Seed A (hi+lo) into BOTH half-buffer copies (plain stores; the implicit
// end-of-kernel agent release makes them visible to k_loop on any XCD).
__device__ __forceinline__ void seed_write(float* ws, int row, int k, float x)
{
    _Float16 hi = (_Float16)x;
    _Float16 lo = (_Float16)((x - (float)hi) * LOSCALE);
    int g = row >> 5, mt = (row >> 4) & 1;
    int lane = (row & 15) | (((k >> 3) & 3) << 4);
    int kt = k >> 5, h = kt >> 3, ktl = kt & 7, elem = k & 7;
    size_t off = ((size_t)g * 64 + (size_t)h * 32) * 1024
               + ((size_t)(mt * 8 + ktl) * 64 + lane) * 16 + (size_t)elem * 2;
    char* L = (char*)(ws + OFF_ABL);
    char* R = (char*)(ws + OFF_ABR);
    *(_Float16*)(L + off) = hi;  *(_Float16*)(L + off + 16384) = lo;
    *(_Float16*)(R + off) = hi;  *(_Float16*)(R + off + 16384) = lo;
}

// ---------------------------------------------------------------------------
// init: LayerNorm(pooled)->h0 ; softmax(fm@wf)->context ; seed A0 ; reset bars
// ---------------------------------------------------------------------------
__global__ void k_init(const float* __restrict__ fm, const float* __restrict__ pooled,
                       const float* __restrict__ gamma, const float* __restrict__ beta,
                       const float* __restrict__ attn_w, float* __restrict__ ws)
{
    int b = blockIdx.x;
    int t = threadIdx.x;                 // 256 threads
    __shared__ float red[256];
    __shared__ float s_sc[49];
    __shared__ float s_aw[49];
    __shared__ float s_ctx[DDIM];

    if (b == 0) {
        if (t < 32) g_bar[t * 32] = 0u;
        if (t == 32) g_cnt = 0u;
    }

    const float* prow = pooled + (size_t)b * DDIM;
    float x0 = prow[t], x1 = prow[t + 256];
    red[t] = x0 + x1;
    __syncthreads();
    for (int s = 128; s > 0; s >>= 1) { if (t < s) red[t] += red[t + s]; __syncthreads(); }
    float mu = red[0] * (1.0f / DDIM);
    __syncthreads();
    float d0 = x0 - mu, d1 = x1 - mu;
    red[t] = d0 * d0 + d1 * d1;
    __syncthreads();
    for (int s = 128; s > 0; s >>= 1) { if (t < s) red[t] += red[t + s]; __syncthreads(); }
    float rstd = rsqrtf(red[0] * (1.0f / DDIM) + LN_EPS);

    float h0 = d0 * rstd * gamma[t]       + beta[t];
    float h1 = d1 * rstd * gamma[t + 256] + beta[t + 256];

    if (t < 49) {
        const float* base = fm + (size_t)b * DDIM * 49 + t;
        float acc = 0.0f;
        for (int d = 0; d < DDIM; ++d) acc += base[(size_t)d * 49] * attn_w[d];
        s_sc[t] = acc;
    }
    __syncthreads();
    if (t == 0) {
        float mx = s_sc[0];
        for (int k = 1; k < 49; ++k) mx = fmaxf(mx, s_sc[k]);
        float sum = 0.0f;
        for (int k = 0; k < 49; ++k) { float e = expf(s_sc[k] - mx); s_aw[k] = e; sum += e; }
        float inv = 1.0f / sum;
        for (int k = 0; k < 49; ++k) s_aw[k] *= inv;
    }
    __syncthreads();

    float* ctx = ws + OFF_CTX + (size_t)b * DDIM;
    for (int d = t; d < DDIM; d += 256) {
        const float* base = fm + ((size_t)b * DDIM + d) * 49;
        float acc = 0.0f;
        for (int k = 0; k < 49; ++k) acc += s_aw[k] * base[k];
        ctx[d] = acc;
        s_ctx[d] = acc;
    }
    __syncthreads();

    seed_write(ws, b, t,       h0 + s_ctx[t]);
    seed_write(ws, b, t + 256, h1 + s_ctx[t + 256]);
}

// ---------------------------------------------------------------------------
// E[v,n] = embed[v,:] . W_ih[n,:] + b_ih[n] + b_hh[n]   (128 x 2048)
// ---------------------------------------------------------------------------
__global__ void k_E(const float* __restrict__ embed, const float* __restrict__ W_ih,
                    const float* __restrict__ b_ih, const float* __restrict__ b_hh,
                    float* __restrict__ ws)
{
    int n = blockIdx.x;
    int t = threadIdx.x;
    __shared__ float wrow[DDIM];
    wrow[t]       = W_ih[(size_t)n * DDIM + t];
    wrow[t + 256] = W_ih[(size_t)n * DDIM + t + 256];
    __syncthreads();
    if (t < VDIM) {
        const float* er = embed + (size_t)t * DDIM;
        float acc = 0.0f;
        for (int d = 0; d < DDIM; ++d) acc += er[d] * wrow[d];
        ws[OFF_E + (size_t)t * FD + n] = acc + b_ih[n] + b_hh[n];
    }
}

__global__ void k_cp(const float* __restrict__ proj_w, float* __restrict__ ws)
{
    int b = blockIdx.x;
    int t = threadIdx.x;                 // 128
    __shared__ float crow[DDIM];
    const float* ctx = ws + OFF_CTX + (size_t)b * DDIM;
    for (int d = t; d < DDIM; d += 128) crow[d] = ctx[d];
    __syncthreads();
    const float* pr = proj_w + (size_t)t * DDIM;
    float acc = 0.0f;
    for (int d = 0; d < DDIM; ++d) acc += crow[d] * pr[d];
    ws[OFF_CP + (size_t)b * VDIM + t] = acc;
}

__global__ void k_bsetup(const float* __restrict__ W_hh, const float* __restrict__ proj_w,
                         float* __restrict__ ws)
{
    int n = blockIdx.x;                  // 0..2175
    int t = threadIdx.x;                 // 256
    const float* src = (n < FD) ? (W_hh + (size_t)n * DDIM)
                                : (proj_w + (size_t)(n - FD) * DDIM);
    _Float16* Bhi = (_Float16*)(ws + OFF_BHI);
    _Float16* Blo = (_Float16*)(ws + OFF_BLO);
    for (int k = t; k < DDIM; k += 256)
        split_write(src[k], Bhi, Blo, n, k);
}

// 8-kt GEMM sweep starting at kt=k0: A from LDS, B from L2-resident global,
// depth-1 B prefetch; accumulators carry across calls.
template<int NT>
__device__ __forceinline__ void gemmK8(const unsigned char* aLds, int lane,
                                       const v8hf* __restrict__ Bh,
                                       const v8hf* __restrict__ Bl,
                                       const int* nts, int k0, v4f* a1, v4f* a2)
{
    v8hf bh[NT], bl[NT];
#pragma unroll
    for (int tt = 0; tt < NT; ++tt) {
        bh[tt] = Bh[((size_t)nts[tt] * 16 + k0) * 64 + lane];
        bl[tt] = Bl[((size_t)nts[tt] * 16 + k0) * 64 + lane];
    }
#pragma unroll
    for (int i = 0; i < 8; ++i) {
        int kt = k0 + i;
        v8hf nbh[NT], nbl[NT];
        if (i < 7) {
#pragma unroll
            for (int tt = 0; tt < NT; ++tt) {
                nbh[tt] = Bh[((size_t)nts[tt] * 16 + kt + 1) * 64 + lane];
                nbl[tt] = Bl[((size_t)nts[tt] * 16 + kt + 1) * 64 + lane];
            }
        }
        v8hf ah = *(const v8hf*)(aLds + kt * 2048 + lane * 16);
        v8hf al = *(const v8hf*)(aLds + kt * 2048 + 1024 + lane * 16);
#pragma unroll
        for (int tt = 0; tt < NT; ++tt) {
            a1[tt] = __builtin_amdgcn_mfma_f32_16x16x32_f16(ah, bh[tt], a1[tt], 0, 0, 0);
            a2[tt] = __builtin_amdgcn_mfma_f32_16x16x32_f16(ah, bl[tt], a2[tt], 0, 0, 0);
            a2[tt] = __builtin_amdgcn_mfma_f32_16x16x32_f16(al, bh[tt], a2[tt], 0, 0, 0);
        }
        if (i < 7) {
#pragma unroll
            for (int tt = 0; tt < NT; ++tt) { bh[tt] = nbh[tt]; bl[tt] = nbl[tt]; }
        }
    }
}

// ---------------------------------------------------------------------------
// Persistent loop, 256 blocks x 512 thr (1/CU). Runtime placement map ->
// rank by (xcd, blk) -> XCD pair p = ranks [64p,64p+64). Group g = p*8+j has
// c0..3 on the pair's first XCD, c4..7 on the second => per-XCD B = HALF
// (2.23 MB, L2-resident). h/A halves split by kt: half0 = kt0..7 (c0..3),
// half1 = kt8..15 (c4..7). Producers dual-write (plain->ABL same-XCD,
// sc0sc1->ABR cross-XCD). Consumers pick per-half: fast -> sc0 from ABL,
// else sc0sc1 from ABR. Local half staged+computed first while remote loads
// fly (vmcnt-split). `out` stores are STREAMING (sc0 sc1): no L2 allocate ->
// no fill-fetch/writeback and, critically, no B-eviction (the round-5
// thrash: 0.5 MB of 804B-stride stores allocated ~16 MB/step of lines).
// ---------------------------------------------------------------------------
__global__ __launch_bounds__(512, 2) void k_loop(
        const float* __restrict__ proj_b, float* __restrict__ ws,
        float* __restrict__ out, const int* __restrict__ sos_p)
{
    const int blk = blockIdx.x;
    const int tid = threadIdx.x;
    const int w = tid >> 6, lane = tid & 63;
    const int s = w >> 1, m = w & 1;     // 4 s-slices x 2 mtiles
    const int l15 = lane & 15, l4 = lane >> 4;

    __shared__ __align__(16) unsigned char smem[65536];

    int xcd_my;
    asm volatile("s_getreg_b32 %0, hwreg(HW_REG_XCC_ID)" : "=s"(xcd_my));

    // ---- placement rendezvous ------------------------------------------
    if (tid == 0) {
        __hip_atomic_store(&g_xcd[blk], xcd_my, RLX, AGENT);
        asm volatile("s_waitcnt vmcnt(0)" ::: "memory");
        __hip_atomic_fetch_add(&g_cnt, 1u, RLX, AGENT);
        unsigned int spins = 0;
        while (__hip_atomic_load(&g_cnt, RLX, AGENT) < 256u) {
            __builtin_amdgcn_s_sleep(2);
            if (++spins > (1u << 22)) break;
        }
    }
    __syncthreads();
    int* xl = (int*)(smem);              // [0,1024)
    int* rk = (int*)(smem + 1024);       // [1024,2048)
    int* bc = (int*)(smem + 2048);       // broadcast {g, c, fast0, fast1}
    if (tid < 256) xl[tid] = __hip_atomic_load(&g_xcd[tid], RLX, AGENT);
    __syncthreads();
    if (tid < 256) {
        int mx = xl[tid], r = 0;
        for (int i = 0; i < 256; ++i) {
            int xi = xl[i];
            if (xi < mx || (xi == mx && i < tid)) ++r;
        }
        rk[tid] = r;
    }
    __syncthreads();
    if (tid == 0) {
        int* order = (int*)(smem + 4096);
        for (int i = 0; i < 256; ++i) order[rk[i]] = i;
        int myr = rk[blk];
        int p = myr >> 6, lr = myr & 63;
        int j, c;
        if (lr < 32) { j = lr >> 2; c = lr & 3; }
        else         { j = (lr - 32) >> 2; c = 4 + ((lr - 32) & 3); }
        int base0 = p * 64 + j * 4;          // half0 producers (c=0..3)
        int base1 = p * 64 + 32 + j * 4;     // half1 producers (c=4..7)
        int x0 = xl[order[base0]], hom0 = 1;
        for (int k = 1; k < 4; ++k) if (xl[order[base0 + k]] != x0) hom0 = 0;
        int x1 = xl[order[base1]], hom1 = 1;
        for (int k = 1; k < 4; ++k) if (xl[order[base1 + k]] != x1) hom1 = 0;
        int mn = xl[0], mxv = xl[0];
        for (int i = 0; i < 256; ++i) { mn = min(mn, xl[i]); mxv = max(mxv, xl[i]); }
        int sane = (mn != mxv);              // garbage XCC_ID map -> force L3
        bc[0] = p * 8 + j;
        bc[1] = c;
        bc[2] = sane && hom0 && (x0 == xl[blk]);
        bc[3] = sane && hom1 && (x1 == xl[blk]);
    }
    __syncthreads();
    const int g = bc[0];
    const int c = bc[1];
    const bool fast0 = (bc[2] != 0);
    const bool fast1 = (bc[3] != 0);
    __syncthreads();

    unsigned int* bar = &g_bar[g * 32];
    const v8hf* Bh = (const v8hf*)(ws + OFF_BHI);
    const v8hf* Bl = (const v8hf*)(ws + OFF_BLO);
    u64* part = (u64*)(ws + OFF_PART);
    char* ABL = (char*)(ws + OFF_ABL);
    char* ABR = (char*)(ws + OFF_ABR);
    const unsigned char* aLds = smem + m * 32768;

    const char* baseH[2];
    bool fH[2] = {fast0, fast1};
    baseH[0] = (fast0 ? ABL : ABR) + ((size_t)g * 64 +  0) * 1024;
    baseH[1] = (fast1 ? ABL : ABR) + ((size_t)g * 64 + 32) * 1024;
    const int lh = fast0 ? 0 : (fast1 ? 1 : (c >> 2));   // stage/compute first
    const int rh = 1 - lh;
    const int hb = c >> 2;                                // half I produce

    const int q = c * 4 + s;
    const int d = q * 16 + l15;          // this lane's gate column
    const int ntsG[4] = {q, q + 32, q + 64, q + 96};
    const int ntsL[1] = {128 + c};
    const int vcol = 16 * c + l15;       // logits column (s==0 waves)

    // persistent per-lane state
    float creg[4], ctxreg[4], cpv[4];
    float pb = proj_b[vcol];
#pragma unroll
    for (int r = 0; r < 4; ++r) {
        int rowg = g * 32 + m * 16 + l4 * 4 + r;
        creg[r] = 0.0f;
        ctxreg[r] = ws[OFF_CTX + (size_t)rowg * DDIM + d];
        cpv[r] = ws[OFF_CP + (size_t)rowg * VDIM + vcol];
    }
    const int sosv = sos_p[0];

    u64* partScr = (u64*)(smem + 16384); // reuse staging area post-GEMM
    int* idsl    = (int*)(smem + 20480);

    const int ktl_t = tid >> 6;          // 0..7 : my staged ktl
    const int ln_t  = tid & 63;
    const size_t soff = (size_t)ktl_t * 1024 + (size_t)ln_t * 16;

    unsigned int tgt = 0;

    for (int tau = 0; tau <= 201; ++tau) {
        const bool doGates = (tau < 201);
        const bool doLog   = (s == 0) && (tau >= 1);

        // ---- stage: local half first, remote in flight ------------------
        v4f Lh0, Ll0, Lh1, Ll1, Rh0, Rl0, Rh1, Rl1;
        {
            const char* pL0 = baseH[lh] + soff;
            const char* pL1 = baseH[lh] + 8192 + soff;
            const char* pR0 = baseH[rh] + soff;
            const char* pR1 = baseH[rh] + 8192 + soff;
            if (fH[lh]) {
                asm volatile("global_load_dwordx4 %0, %1, off sc0" : "=v"(Lh0) : "v"(pL0) : "memory");
                asm volatile("global_load_dwordx4 %0, %1, off sc0" : "=v"(Ll0) : "v"(pL0 + 16384) : "memory");
                asm volatile("global_load_dwordx4 %0, %1, off sc0" : "=v"(Lh1) : "v"(pL1) : "memory");
                asm volatile("global_load_dwordx4 %0, %1, off sc0" : "=v"(Ll1) : "v"(pL1 + 16384) : "memory");
            } else {
                asm volatile("global_load_dwordx4 %0, %1, off sc0 sc1" : "=v"(Lh0) : "v"(pL0) : "memory");
                asm volatile("global_load_dwordx4 %0, %1, off sc0 sc1" : "=v"(Ll0) : "v"(pL0 + 16384) : "memory");
                asm volatile("global_load_dwordx4 %0, %1, off sc0 sc1" : "=v"(Lh1) : "v"(pL1) : "memory");
                asm volatile("global_load_dwordx4 %0, %1, off sc0 sc1" : "=v"(Ll1) : "v"(pL1 + 16384) : "memory");
            }
            if (fH[rh]) {
                asm volatile("global_load_dwordx4 %0, %1, off sc0" : "=v"(Rh0) : "v"(pR0) : "memory");
                asm volatile("global_load_dwordx4 %0, %1, off sc0" : "=v"(Rl0) : "v"(pR0 + 16384) : "memory");
                asm volatile("global_load_dwordx4 %0, %1, off sc0" : "=v"(Rh1) : "v"(pR1) : "memory");
                asm volatile("global_load_dwordx4 %0, %1, off sc0" : "=v"(Rl1) : "v"(pR1 + 16384) : "memory");
            } else {
                asm volatile("global_load_dwordx4 %0, %1, off sc0 sc1" : "=v"(Rh0) : "v"(pR0) : "memory");
                asm volatile("global_load_dwordx4 %0, %1, off sc0 sc1" : "=v"(Rl0) : "v"(pR0 + 16384) : "memory");
                asm volatile("global_load_dwordx4 %0, %1, off sc0 sc1" : "=v"(Rh1) : "v"(pR1) : "memory");
                asm volatile("global_load_dwordx4 %0, %1, off sc0 sc1" : "=v"(Rl1) : "v"(pR1 + 16384) : "memory");
            }
        }
        asm volatile("s_waitcnt vmcnt(4)" ::: "memory");   // 4 oldest = local
        __builtin_amdgcn_sched_barrier(0);
        {
            int kt = lh * 8 + ktl_t;
            *(v4f*)(smem +         kt * 2048 +        ln_t * 16) = Lh0;
            *(v4f*)(smem +         kt * 2048 + 1024 + ln_t * 16) = Ll0;
            *(v4f*)(smem + 32768 + kt * 2048 +        ln_t * 16) = Lh1;
            *(v4f*)(smem + 32768 + kt * 2048 + 1024 + ln_t * 16) = Ll1;
        }
        __syncthreads();

        // ---- chunk 1: local-half kts (remote loads still in flight) -----
        v4f a1g[4], a2g[4], a1l[1], a2l[1];
#pragma unroll
        for (int tt = 0; tt < 4; ++tt) {
            a1g[tt] = (v4f){0.f, 0.f, 0.f, 0.f};
            a2g[tt] = (v4f){0.f, 0.f, 0.f, 0.f};
        }
        a1l[0] = (v4f){0.f, 0.f, 0.f, 0.f};
        a2l[0] = (v4f){0.f, 0.f, 0.f, 0.f};
        if (doGates) gemmK8<4>(aLds, lane, Bh, Bl, ntsG, lh * 8, a1g, a2g);
        if (doLog)   gemmK8<1>(aLds, lane, Bh, Bl, ntsL, lh * 8, a1l, a2l);

        asm volatile("s_waitcnt vmcnt(0)" ::: "memory");
        __builtin_amdgcn_sched_barrier(0);
        {
            int kt = rh * 8 + ktl_t;
            *(v4f*)(smem +         kt * 2048 +        ln_t * 16) = Rh0;
            *(v4f*)(smem +         kt * 2048 + 1024 + ln_t * 16) = Rl0;
            *(v4f*)(smem + 32768 + kt * 2048 +        ln_t * 16) = Rh1;
            *(v4f*)(smem + 32768 + kt * 2048 + 1024 + ln_t * 16) = Rl1;
        }
        __syncthreads();

        // ---- chunk 2: remote-half kts -----------------------------------
        if (doGates) gemmK8<4>(aLds, lane, Bh, Bl, ntsG, rh * 8, a1g, a2g);
        if (doLog)   gemmK8<1>(aLds, lane, Bh, Bl, ntsL, rh * 8, a1l, a2l);

        // ---- logits out (streaming) + partial argmax --------------------
        if (doLog) {
            float lgv[4];
#pragma unroll
            for (int r = 0; r < 4; ++r) {
                float lg = (a1l[0][r] + a2l[0][r] * INV_LOSCALE - cpv[r]) + pb;
                lgv[r] = lg;
                int rowg = g * 32 + m * 16 + l4 * 4 + r;
                st4_stream(&out[((size_t)rowg * VDIM + vcol) * TDIM + (tau - 1)], lg);
            }
            if (tau < 201) {
#pragma unroll
                for (int r = 0; r < 4; ++r) {
                    float bv = lgv[r];
                    int   bi = vcol;
#pragma unroll
                    for (int off = 1; off <= 8; off <<= 1) {
                        float ov = __shfl_xor(bv, off, 64);
                        int   oi = __shfl_xor(bi, off, 64);
                        if (ov > bv || (ov == bv && oi < bi)) { bv = ov; bi = oi; }
                    }
                    if (l15 == 0) {
                        int rowg = g * 32 + m * 16 + l4 * 4 + r;
                        u64 pk = ((u64)__float_as_uint(bv) << 32) | (unsigned int)bi;
                        st8_l3(&part[(size_t)rowg * 8 + c], pk);
                    }
                }
            }
        }
        if (tau == 201) break;

        tgt += 8; group_barrier(bar, tgt);       // logits/partials published

        // ---- combine argmax (each block locally; ascending c, strict >) --
        if (tau >= 1) {
            if (tid < 256) {
                int rl = tid >> 3, cc = tid & 7;
                partScr[tid] = ld8_l3(&part[(size_t)(g * 32 + rl) * 8 + cc]);
            }
        }
        __syncthreads();
        if (tau >= 1 && tid < 32) {
            float bv = -1e38f; int bi = 0;
#pragma unroll
            for (int cc = 0; cc < 8; ++cc) {
                u64 u = partScr[tid * 8 + cc];
                float v = __uint_as_float((unsigned int)(u >> 32));
                int   i = (int)(u & 0xffffffffu);
                if (cc == 0 || v > bv) { bv = v; bi = i; }
            }
            idsl[tid] = bi;
        }
        __syncthreads();

        // ---- pointwise LSTM in registers --------------------------------
        {
            const int ktl = (d >> 5) & 1;
            const int sel = (d >> 3) & 3;
            const int elem = d & 7;
#pragma unroll
            for (int r = 0; r < 4; ++r) {
                int rl = m * 16 + l4 * 4 + r;
                int id = (tau == 0) ? sosv : idsl[rl];
                const float* er = ws + OFF_E + (size_t)id * FD;
                float gi = a1g[0][r] + a2g[0][r] * INV_LOSCALE + er[d];
                float gf = a1g[1][r] + a2g[1][r] * INV_LOSCALE + er[d + 512];
                float gg = a1g[2][r] + a2g[2][r] * INV_LOSCALE + er[d + 1024];
                float go = a1g[3][r] + a2g[3][r] * INV_LOSCALE + er[d + 1536];
                float si = 1.0f / (1.0f + expf(-gi));
                float sf = 1.0f / (1.0f + expf(-gf));
                float so = 1.0f / (1.0f + expf(-go));
                float cn = sf * creg[r] + si * tanhf(gg);
                creg[r] = cn;
                float hn = so * tanhf(cn);
                float av = hn + ctxreg[r];
                _Float16 hh = (_Float16)av;
                _Float16 hl = (_Float16)((av - (float)hh) * LOSCALE);
                int la = (l4 * 4 + r) | (sel << 4);
                size_t so2 = (size_t)(((m * 2 + ktl) * 2 + 0) * 64 + la) * 16 + elem * 2;
                *(unsigned short*)(smem + so2)        = *(unsigned short*)&hh;
                *(unsigned short*)(smem + so2 + 1024) = *(unsigned short*)&hl;
            }
        }
        __syncthreads();
        // cooperative A-slice store: dual-write 8 KB (L plain + R sc1)
        {
            int m2 = tid >> 8, ktl2 = (tid >> 7) & 1, hl2 = (tid >> 6) & 1, ln2 = tid & 63;
            v4f v = *(const v4f*)(smem + (size_t)(((m2 * 2 + ktl2) * 2 + hl2) * 64 + ln2) * 16);
            int klh = (c & 3) * 2 + ktl2;
            size_t off = ((size_t)g * 64 + (size_t)hb * 32) * 1024
                       + ((size_t)(m2 * 8 + klh) * 64 + ln2) * 16
                       + (hl2 ? 16384 : 0);
            *(volatile v4f*)(ABL + off) = v;
            st16_l3(ABR + off, v);
        }

        tgt += 8; group_barrier(bar, tgt);       // A_{tau+1} published
    }
}

extern "C" void kernel_launch(void* const* d_in, const int* in_sizes, int n_in,
                              void* d_out, int out_size, void* d_ws, size_t ws_size,
                              hipStream_t stream)
{
    const float* fm     = (const float*)d_in[0];
    const float* pooled = (const float*)d_in[1];
    const float* gamma  = (const float*)d_in[2];
    const float* beta   = (const float*)d_in[3];
    const float* W_ih   = (const float*)d_in[4];
    const float* W_hh   = (const float*)d_in[5];
    const float* b_ih   = (const float*)d_in[6];
    const float* b_hh   = (const float*)d_in[7];
    const float* embed  = (const float*)d_in[8];
    const float* attn_w = (const float*)d_in[9];
    // d_in[10] = attn_b : provably unused (softmax shift invariance)
    const float* proj_w = (const float*)d_in[11];
    const float* proj_b = (const float*)d_in[12];
    const int*   sos_p  = (const int*)d_in[13];

    float* ws  = (float*)d_ws;
    float* out = (float*)d_out;

    k_init<<<BDIM, 256, 0, stream>>>(fm, pooled, gamma, beta, attn_w, ws);
    k_E<<<FD, 256, 0, stream>>>(embed, W_ih, b_ih, b_hh, ws);
    k_cp<<<BDIM, 128, 0, stream>>>(proj_w, ws);
    k_bsetup<<<FD + VDIM, 256, 0, stream>>>(W_hh, proj_w, ws);

    // Entire 201-step recurrence in ONE persistent kernel.
    // Round-5 structure (verified passing) + ONE change: streaming `out`
    // stores (sc0 sc1) to stop L2 write-allocate thrash of the B frags.
    k_loop<<<dim3(256), 512, 0, stream>>>(proj_b, ws, out, sos_p);
}